// Round 1
// 2548.380 us; speedup vs baseline: 1.1340x; 1.1340x over previous
//
#include <hip/hip_runtime.h>

// EncoderLayer: S=50, L=1024, D=768, D4=192. fp32 in/out, bf16 MFMA compute.
// All large GEMMs normalized to NT bf16 (A [M,K], Bt [N,K]) and run through a
// 128x128-tile m97-style kernel: global_load_lds(16B) staging with XOR-swizzled
// per-lane SOURCE addresses (linear LDS dest, swizzle-on-read), 4 waves x 4x4
// fragments of mfma_f32_16x16x32_bf16. Weights are transposed+converted to
// bf16 on the fly into a scratch arena (dead G region). Tiny cross GEMMs keep
// the old 64x64 kernel.

typedef __bf16 bf16x8 __attribute__((ext_vector_type(8)));
typedef __bf16 bf16x4 __attribute__((ext_vector_type(4)));
typedef float f32x4 __attribute__((ext_vector_type(4)));

typedef __attribute__((address_space(3))) void lds_t;
typedef __attribute__((address_space(1))) const void gbl_t;

__device__ __forceinline__ void gload16(const void* g, void* l) {
    __builtin_amdgcn_global_load_lds((gbl_t*)g, (lds_t*)l, 16, 0, 0);
}

// ---------------- fast 128x128 NT GEMM: C[M,N] = A[M,K] * Bt[N,K]^T ---------
// A, Bt bf16. K % 64 == 0. OOB M/N rows are clamped on load (results masked at
// store). Optional fp32 bias[N] (+batch stride) and relu.
__global__ __launch_bounds__(256) void gemm128_k(
    const __bf16* __restrict__ A, const __bf16* __restrict__ Bt, __bf16* __restrict__ C,
    int M, int N, int K, int lda, int ldb, int ldc,
    long long sA, long long sB, long long sC,
    const float* __restrict__ bias, long long sBias, int relu)
{
    __shared__ __bf16 As[128 * 64];   // linear: row*64 + chunk*8 (+swizzle)
    __shared__ __bf16 Bs[128 * 64];

    const int batch = blockIdx.z;
    A  += (long long)batch * sA;
    Bt += (long long)batch * sB;
    C  += (long long)batch * sC;

    const int m0 = blockIdx.x * 128;
    const int n0 = blockIdx.y * 128;
    const int tid  = threadIdx.x;
    const int lane = tid & 63;
    const int wave = tid >> 6;
    const int wr = wave >> 1, wc = wave & 1;     // 2x2 waves, 64x64 each
    const int l15 = lane & 15;

    // per-thread staging sources. granule g = r*256+tid covers (row = g>>3,
    // chunk = g&7); source chunk is (chunk ^ (row&7)) so that a swizzled READ
    // at chunk (cg ^ (row&7)) returns global chunk cg. LDS dest is linear.
    const __bf16* aSrc[4];
    const __bf16* bSrc[4];
    #pragma unroll
    for (int r = 0; r < 4; r++) {
        const int g   = r * 256 + tid;
        const int row = g >> 3;
        const int ch  = (g & 7) ^ (row & 7);
        int ra = m0 + row; if (ra > M - 1) ra = M - 1;
        int rb = n0 + row; if (rb > N - 1) rb = N - 1;
        aSrc[r] = A  + (long long)ra * lda + (ch << 3);
        bSrc[r] = Bt + (long long)rb * ldb + (ch << 3);
    }
    __bf16* aD = As + wave * 512;    // wave-uniform LDS base (HW: +lane*16B)
    __bf16* bD = Bs + wave * 512;

    f32x4 acc[4][4];
    #pragma unroll
    for (int i = 0; i < 4; i++)
        #pragma unroll
        for (int j = 0; j < 4; j++) acc[i][j] = f32x4{0.f, 0.f, 0.f, 0.f};

    for (int kb = 0; kb < K; kb += 64) {
        #pragma unroll
        for (int r = 0; r < 4; r++) gload16(aSrc[r] + kb, aD + r * 2048);
        #pragma unroll
        for (int r = 0; r < 4; r++) gload16(bSrc[r] + kb, bD + r * 2048);
        __syncthreads();    // drains vmcnt: LDS tiles ready

        #pragma unroll
        for (int ks = 0; ks < 2; ks++) {
            const int cg = ks * 4 + (lane >> 4);           // global k-chunk
            const int so = ((cg ^ (l15 & 7)) << 3);        // swizzled elem off
            bf16x8 av[4], bv[4];
            #pragma unroll
            for (int mi = 0; mi < 4; mi++)
                av[mi] = *(const bf16x8*)&As[(wr * 64 + mi * 16 + l15) * 64 + so];
            #pragma unroll
            for (int ni = 0; ni < 4; ni++)
                bv[ni] = *(const bf16x8*)&Bs[(wc * 64 + ni * 16 + l15) * 64 + so];
            #pragma unroll
            for (int mi = 0; mi < 4; mi++)
                #pragma unroll
                for (int ni = 0; ni < 4; ni++)
                    acc[mi][ni] = __builtin_amdgcn_mfma_f32_16x16x32_bf16(
                        av[mi], bv[ni], acc[mi][ni], 0, 0, 0);
        }
        __syncthreads();    // MFMA reads done before next staging overwrite
    }

    // epilogue: C/D layout col=lane&15, row=(lane>>4)*4+reg  [m89-verified]
    const int rb4 = (lane >> 4) << 2;
    #pragma unroll
    for (int mi = 0; mi < 4; mi++) {
        #pragma unroll
        for (int ni = 0; ni < 4; ni++) {
            const int col = n0 + wc * 64 + ni * 16 + l15;
            if (col >= N) continue;
            float bvl = 0.f;
            if (bias) bvl = bias[(long long)batch * sBias + col];
            #pragma unroll
            for (int r = 0; r < 4; r++) {
                const int row = m0 + wr * 64 + mi * 16 + rb4 + r;
                if (row < M) {
                    float v = acc[mi][ni][r] + bvl;
                    if (relu) v = fmaxf(v, 0.f);
                    C[(long long)row * ldc + col] = (__bf16)v;
                }
            }
        }
    }
}

// ---------------- transpose + convert: in[R,C] -> out[C,R] bf16 -------------
// INF32=1: fp32 input; INF32=0: bf16 input. R,C multiples of 32. Batched (z).
template<int INF32>
__global__ __launch_bounds__(256) void trans_k(
    const void* __restrict__ in, __bf16* __restrict__ out,
    int R, int Cn, long long sIn, long long sOut)
{
    __shared__ float tile[32][33];
    const int b  = blockIdx.z;
    const int r0 = blockIdx.x * 32, c0 = blockIdx.y * 32;
    const int t  = threadIdx.x;
    {
        const int rl = t >> 3;
        const int cl = (t & 7) << 2;
        const long long src = (long long)b * sIn + (long long)(r0 + rl) * Cn + c0 + cl;
        if (INF32) {
            float4 v = *(const float4*)((const float*)in + src);
            tile[rl][cl + 0] = v.x; tile[rl][cl + 1] = v.y;
            tile[rl][cl + 2] = v.z; tile[rl][cl + 3] = v.w;
        } else {
            bf16x4 v = *(const bf16x4*)((const __bf16*)in + src);
            tile[rl][cl + 0] = (float)v[0]; tile[rl][cl + 1] = (float)v[1];
            tile[rl][cl + 2] = (float)v[2]; tile[rl][cl + 3] = (float)v[3];
        }
    }
    __syncthreads();
    {
        const int c2 = t >> 3;
        const int r2 = (t & 7) << 2;
        bf16x4 o;
        o[0] = (__bf16)tile[r2 + 0][c2]; o[1] = (__bf16)tile[r2 + 1][c2];
        o[2] = (__bf16)tile[r2 + 2][c2]; o[3] = (__bf16)tile[r2 + 3][c2];
        *(bf16x4*)(out + (long long)b * sOut + (long long)(c0 + c2) * R + r0 + r2) = o;
    }
}

// ---------------- legacy 64x64 GEMM (kept only for the tiny cross GEMMs) ----
template<int BNN, int BF32>
__global__ __launch_bounds__(256) void gemm_k(
    const __bf16* __restrict__ A, const void* __restrict__ Bv, __bf16* __restrict__ C,
    int M, int N, int K, int Kb,
    int lda, int ldb, int ldc,
    long long sA, long long sB, long long sC,
    const float* __restrict__ bias, long long sBias, int relu)
{
    __shared__ __bf16 As[64][72];
    __shared__ __bf16 Bs[64][72];

    const int batch = blockIdx.z;
    A += (long long)batch * sA;
    C += (long long)batch * sC;

    const int m0 = blockIdx.x * 64;
    const int n0 = blockIdx.y * 64;
    const int tid = threadIdx.x;
    const int lane = tid & 63;
    const int wave = tid >> 6;
    const int wr = wave >> 1, wc = wave & 1;

    f32x4 acc[2][2];
    #pragma unroll
    for (int i = 0; i < 2; i++)
        #pragma unroll
        for (int j = 0; j < 2; j++) acc[i][j] = f32x4{0.f, 0.f, 0.f, 0.f};

    for (int kb = 0; kb < K; kb += 64) {
        {
            const int row = tid >> 2;
            const int cs = (tid & 3) << 4;
            const int gr = m0 + row;
            __bf16* dst = &As[row][cs];
            if (gr < M) {
                const __bf16* src = A + (long long)gr * lda + kb + cs;
                *(bf16x8*)dst       = *(const bf16x8*)src;
                *(bf16x8*)(dst + 8) = *(const bf16x8*)(src + 8);
            } else {
                #pragma unroll
                for (int i = 0; i < 16; i++) dst[i] = (__bf16)0.f;
            }
        }
        if (BNN) {
            const int kk = tid >> 2;
            const int ns = (tid & 3) << 4;
            const int gk = kb + kk;
            const bool kok = gk < Kb;
            const __bf16* src = (const __bf16*)Bv + (long long)batch * sB
                              + (long long)gk * ldb + n0 + ns;
            if (kok && (n0 + ns + 16 <= N)) {
                bf16x8 v0 = *(const bf16x8*)src;
                bf16x8 v1 = *(const bf16x8*)(src + 8);
                #pragma unroll
                for (int i = 0; i < 8; i++) Bs[ns + i][kk] = v0[i];
                #pragma unroll
                for (int i = 0; i < 8; i++) Bs[ns + 8 + i][kk] = v1[i];
            } else {
                for (int i = 0; i < 16; i++) {
                    const int n = n0 + ns + i;
                    Bs[ns + i][kk] = (kok && n < N) ? src[i] : (__bf16)0.f;
                }
            }
        } else {
            const int row = tid >> 2;
            const int cs = (tid & 3) << 4;
            const int gn = n0 + row;
            __bf16* dst = &Bs[row][cs];
            if (gn < N) {
                const __bf16* src = (const __bf16*)Bv + (long long)batch * sB
                                  + (long long)gn * ldb + kb + cs;
                *(bf16x8*)dst       = *(const bf16x8*)src;
                *(bf16x8*)(dst + 8) = *(const bf16x8*)(src + 8);
            } else {
                #pragma unroll
                for (int i = 0; i < 16; i++) dst[i] = (__bf16)0.f;
            }
        }
        __syncthreads();

        #pragma unroll
        for (int ks = 0; ks < 64; ks += 32) {
            const int kf = ks + ((lane >> 4) << 3);
            bf16x8 av[2], bv[2];
            #pragma unroll
            for (int mi = 0; mi < 2; mi++)
                av[mi] = *(const bf16x8*)&As[wr * 32 + mi * 16 + (lane & 15)][kf];
            #pragma unroll
            for (int ni = 0; ni < 2; ni++)
                bv[ni] = *(const bf16x8*)&Bs[wc * 32 + ni * 16 + (lane & 15)][kf];
            #pragma unroll
            for (int mi = 0; mi < 2; mi++)
                #pragma unroll
                for (int ni = 0; ni < 2; ni++)
                    acc[mi][ni] = __builtin_amdgcn_mfma_f32_16x16x32_bf16(
                        av[mi], bv[ni], acc[mi][ni], 0, 0, 0);
        }
        __syncthreads();
    }

    const int rb = (lane >> 4) << 2;
    const int cc = lane & 15;
    #pragma unroll
    for (int mi = 0; mi < 2; mi++) {
        #pragma unroll
        for (int ni = 0; ni < 2; ni++) {
            const int col = n0 + wc * 32 + ni * 16 + cc;
            if (col >= N) continue;
            float bvl = 0.f;
            if (bias) bvl = bias[(long long)batch * sBias + col];
            #pragma unroll
            for (int r = 0; r < 4; r++) {
                const int row = m0 + wr * 32 + mi * 16 + rb + r;
                if (row < M) {
                    float v = acc[mi][ni][r] + bvl;
                    if (relu) v = fmaxf(v, 0.f);
                    C[(long long)row * ldc + col] = (__bf16)v;
                }
            }
        }
    }
}

// ---------------- reductions ----------------
__device__ __forceinline__ float wave_sum(float v) {
    #pragma unroll
    for (int o = 32; o > 0; o >>= 1) v += __shfl_xor(v, o);
    return v;
}
__device__ __forceinline__ float wave_max(float v) {
    #pragma unroll
    for (int o = 32; o > 0; o >>= 1) v = fmaxf(v, __shfl_xor(v, o));
    return v;
}

// softmax over 1024 cols, in-place bf16 (vectorized 4/thread)
__global__ __launch_bounds__(256) void softmax_self_k(__bf16* __restrict__ u, float scale) {
    __shared__ float red[4];
    const long long row = blockIdx.x;
    __bf16* p = u + row * 1024;
    const int t = threadIdx.x;
    bf16x4 raw = *(const bf16x4*)(p + t * 4);
    float v[4];
    float mx = -1e30f;
    #pragma unroll
    for (int i = 0; i < 4; i++) { v[i] = (float)raw[i]; mx = fmaxf(mx, v[i]); }
    mx = wave_max(mx);
    if ((t & 63) == 0) red[t >> 6] = mx;
    __syncthreads();
    mx = fmaxf(fmaxf(red[0], red[1]), fmaxf(red[2], red[3]));
    float s = 0.f;
    #pragma unroll
    for (int i = 0; i < 4; i++) { v[i] = __expf(scale * (v[i] - mx)); s += v[i]; }
    s = wave_sum(s);
    __syncthreads();
    if ((t & 63) == 0) red[t >> 6] = s;
    __syncthreads();
    s = red[0] + red[1] + red[2] + red[3];
    const float inv = 1.f / s;
    bf16x4 o;
    #pragma unroll
    for (int i = 0; i < 4; i++) o[i] = (__bf16)(v[i] * inv);
    *(bf16x4*)(p + t * 4) = o;
}

// cross softmax: 4 rows/block (1 wave each); 50 valid cols of 64, pads -> 0
__global__ __launch_bounds__(256) void softmax_cross_k(__bf16* __restrict__ u, float scale) {
    const long long row = (long long)blockIdx.x * 4 + (threadIdx.x >> 6);
    __bf16* p = u + row * 64;
    const int lane = threadIdx.x & 63;
    float v = (lane < 50) ? (float)p[lane] : -1e30f;
    float mx = wave_max(v);
    float e = (lane < 50) ? __expf(scale * (v - mx)) : 0.f;
    float s = wave_sum(e);
    p[lane] = (__bf16)(e / s);
}

// out = LN(x + h) * g + b. 192 threads, 4 elems/thread (vectorized).
// mode 0: rows [S*L], g/b per s=(r>>10). mode 1 (cross): rows [L*S] (r=l*50+s),
// shared g/b, out row = s*1024+l. outf32: fp32 out (d_out) else bf16 ws.
__global__ __launch_bounds__(192) void add_ln_k(
    const __bf16* __restrict__ x, const __bf16* __restrict__ h, void* __restrict__ out,
    const float* __restrict__ g, const float* __restrict__ b, int mode, int outf32)
{
    __shared__ float red[3];
    const long long r = blockIdx.x;
    const __bf16* xr = x + r * 768;
    const __bf16* hr = h + r * 768;
    long long orow; const float *gp, *bp;
    if (mode == 0) {
        orow = r;
        const long long s = r >> 10;
        gp = g + s * 768; bp = b + s * 768;
    } else {
        const long long l = r / 50, s2 = r % 50;
        orow = s2 * 1024 + l;
        gp = g; bp = b;
    }
    const int t = threadIdx.x;
    const int d = t * 4;
    bf16x4 xv = *(const bf16x4*)(xr + d);
    bf16x4 hv = *(const bf16x4*)(hr + d);
    float v[4]; float sum = 0.f;
    #pragma unroll
    for (int i = 0; i < 4; i++) { v[i] = (float)xv[i] + (float)hv[i]; sum += v[i]; }
    sum = wave_sum(sum);
    if ((t & 63) == 0) red[t >> 6] = sum;
    __syncthreads();
    const float mean = (red[0] + red[1] + red[2]) * (1.f / 768.f);
    float vs = 0.f;
    #pragma unroll
    for (int i = 0; i < 4; i++) { const float dd = v[i] - mean; vs += dd * dd; }
    vs = wave_sum(vs);
    __syncthreads();
    if ((t & 63) == 0) red[t >> 6] = vs;
    __syncthreads();
    const float rstd = rsqrtf((red[0] + red[1] + red[2]) * (1.f / 768.f) + 1e-5f);
    float4 gv = *(const float4*)(gp + d);
    float4 bv = *(const float4*)(bp + d);
    const float o0 = (v[0] - mean) * rstd * gv.x + bv.x;
    const float o1 = (v[1] - mean) * rstd * gv.y + bv.y;
    const float o2 = (v[2] - mean) * rstd * gv.z + bv.z;
    const float o3 = (v[3] - mean) * rstd * gv.w + bv.w;
    if (outf32) {
        float4 o{o0, o1, o2, o3};
        *(float4*)((float*)out + orow * 768 + d) = o;
    } else {
        bf16x4 o;
        o[0] = (__bf16)o0; o[1] = (__bf16)o1; o[2] = (__bf16)o2; o[3] = (__bf16)o3;
        *(bf16x4*)((__bf16*)out + orow * 768 + d) = o;
    }
}

// [S,L,D] -> [L,S,D] (bf16 ws -> bf16 ws), vectorized: 2 rows/block, 96 thr/row
__global__ __launch_bounds__(192) void transpose_sl_k(const __bf16* __restrict__ in,
                                                      __bf16* __restrict__ out) {
    const long long r = (long long)blockIdx.x * 2 + (threadIdx.x >= 96);
    const int c = (threadIdx.x % 96) * 8;
    const long long s = r >> 10, l = r & 1023;
    *(bf16x8*)(out + (l * 50 + s) * 768 + c) = *(const bf16x8*)(in + r * 768 + c);
}

// fp32 -> bf16, 8 elems/thread
__global__ __launch_bounds__(256) void cvt_f32_bf16_k(const float* __restrict__ in,
                                                      __bf16* __restrict__ out) {
    const long long i = ((long long)blockIdx.x * 256 + threadIdx.x) * 8;
    float4 a = *(const float4*)(in + i);
    float4 b = *(const float4*)(in + i + 4);
    bf16x8 o;
    o[0] = (__bf16)a.x; o[1] = (__bf16)a.y; o[2] = (__bf16)a.z; o[3] = (__bf16)a.w;
    o[4] = (__bf16)b.x; o[5] = (__bf16)b.y; o[6] = (__bf16)b.z; o[7] = (__bf16)b.w;
    *(bf16x8*)(out + i) = o;
}

extern "C" void kernel_launch(void* const* d_in, const int* in_sizes, int n_in,
                              void* d_out, int out_size, void* d_ws, size_t ws_size,
                              hipStream_t stream)
{
    const float SCALE = 0.07216878364870322f;   // 1/sqrt(192)
    auto inf = [&](int i) { return (const float*)d_in[i]; };

    // workspace carve (bytes), all 16B-aligned
    char* w = (char*)d_ws;
    __bf16* xw = (__bf16*)(w + 0LL);            // [S,L,D]   current x (bf16)
    __bf16* hw = (__bf16*)(w + 78643200LL);     // [S,L,D]   h / x^T scratch
    __bf16* tw = (__bf16*)(w + 157286400LL);    // [S,L,D]   t = a@x
    __bf16* xt = (__bf16*)(w + 235929600LL);    // [L,S,D]   cross transpose
    __bf16* qw = (__bf16*)(w + 314572800LL);    // [S,L,D4]
    __bf16* kw = (__bf16*)(w + 334233600LL);    // [S,L,D4]
    __bf16* G  = (__bf16*)(w + 353894400LL);    // [S,L,L] scores/probs (bf16)
    __bf16* wa = G;                             // weight^T arena (aliases dead G)
    if (ws_size < 458752000ULL) return;

    auto g128 = [&](const __bf16* A, const __bf16* Bt, __bf16* C,
                    int M, int N, int K, int lda, int ldb, int ldc,
                    long long sA, long long sB, long long sC, int batch,
                    const float* bias, long long sBias, int relu) {
        dim3 grid((M + 127) / 128, (N + 127) / 128, batch);
        gemm128_k<<<grid, dim3(256), 0, stream>>>(A, Bt, C, M, N, K, lda, ldb, ldc,
                                                  sA, sB, sC, bias, sBias, relu);
    };
    // weight transpose+convert: W fp32 [R,Cn] -> wa bf16 [Cn,R], batched
    auto transw = [&](const float* W, __bf16* outp, int R, int Cn, int batch) {
        dim3 grid(R / 32, Cn / 32, batch);
        trans_k<1><<<grid, dim3(256), 0, stream>>>(W, outp, R, Cn,
                                                   (long long)R * Cn, (long long)R * Cn);
    };

    // x (fp32) -> xw (bf16)
    cvt_f32_bf16_k<<<19200, 256, 0, stream>>>(inf(0), xw);

    auto self_attn = [&](const float* Wq, const float* Wk, const float* Wv,
                         const float* g, const float* b) {
        transw(Wq, wa, 768, 192, 50);
        g128(xw, wa, qw, 1024, 192, 768, 768, 768, 192,
             786432LL, 147456LL, 196608LL, 50, nullptr, 0, 0);
        transw(Wk, wa, 768, 192, 50);
        g128(xw, wa, kw, 1024, 192, 768, 768, 768, 192,
             786432LL, 147456LL, 196608LL, 50, nullptr, 0, 0);
        g128(qw, kw, G, 1024, 1024, 192, 192, 192, 1024,
             196608LL, 196608LL, 1048576LL, 50, nullptr, 0, 0);
        softmax_self_k<<<51200, 256, 0, stream>>>(G, SCALE);
        {   // xw^T (bf16) -> hw for NT AV gemm
            dim3 grid(32, 24, 50);
            trans_k<0><<<grid, dim3(256), 0, stream>>>(xw, hw, 1024, 768,
                                                       786432LL, 786432LL);
        }
        g128(G, hw, tw, 1024, 768, 1024, 1024, 1024, 768,
             1048576LL, 786432LL, 786432LL, 50, nullptr, 0, 0);
        transw(Wv, wa, 768, 768, 50);       // G probs dead now; arena safe
        g128(tw, wa, hw, 1024, 768, 768, 768, 768, 768,
             786432LL, 589824LL, 786432LL, 50, nullptr, 0, 0);
        add_ln_k<<<51200, 192, 0, stream>>>(xw, hw, xw, g, b, 0, 0);
    };
    auto mlp = [&](const float* W1, const float* b1, const float* W2, const float* b2,
                   const float* g, const float* b, void* outp, int outf32) {
        transw(W1, wa, 768, 192, 50);
        g128(xw, wa, qw, 1024, 192, 768, 768, 768, 192,
             786432LL, 147456LL, 196608LL, 50, b1, 192LL, 1);
        transw(W2, wa, 192, 768, 50);
        g128(qw, wa, hw, 1024, 768, 192, 192, 192, 768,
             196608LL, 147456LL, 786432LL, 50, b2, 768LL, 0);
        add_ln_k<<<51200, 192, 0, stream>>>(xw, hw, outp, g, b, 0, outf32);
    };

    // stage 1: pre self-attn + ln1
    self_attn(inf(1), inf(2), inf(3), inf(4), inf(5));
    // stage 2: pre MLP + ln4p
    mlp(inf(6), inf(7), inf(8), inf(9), inf(10), inf(11), xw, 0);

    // stage 3: cross-step attention + ln2 (shared weights)
    transpose_sl_k<<<25600, 192, 0, stream>>>(xw, xt);
    transw(inf(12), wa, 768, 192, 1);
    g128(xt, wa, qw, 51200, 192, 768, 768, 768, 192, 0, 0, 0, 1, nullptr, 0, 0);
    transw(inf(13), wa, 768, 192, 1);
    g128(xt, wa, kw, 51200, 192, 768, 768, 768, 192, 0, 0, 0, 1, nullptr, 0, 0);
    {   // tiny QK^T: M=N=50, K=192, batch 1024 — legacy kernel
        dim3 grid(1, 1, 1024);
        gemm_k<0, 0><<<grid, dim3(256), 0, stream>>>(qw, kw, G, 50, 50, 192, 192,
                                                     192, 192, 64, 9600LL, 9600LL,
                                                     3200LL, nullptr, 0, 0);
    }
    softmax_cross_k<<<12800, 256, 0, stream>>>(G, SCALE);
    {   // tiny AV: M=50, N=768, K=64 (Kb=50), batch 1024 — legacy kernel
        dim3 grid(1, 12, 1024);
        gemm_k<1, 0><<<grid, dim3(256), 0, stream>>>(G, xt, tw, 50, 768, 64, 50,
                                                     64, 768, 768, 3200LL, 38400LL,
                                                     38400LL, nullptr, 0, 0);
    }
    transw(inf(14), qw, 768, 768, 1);       // qw dead after QK^T; holds cWv^T
    g128(tw, qw, hw, 51200, 768, 768, 768, 768, 768, 0, 0, 0, 1, nullptr, 0, 0);
    add_ln_k<<<51200, 192, 0, stream>>>(xt, hw, xw, inf(15), inf(16), 1, 0);

    // stage 4: post self-attn + ln3
    self_attn(inf(17), inf(18), inf(19), inf(20), inf(21));
    // stage 5: post MLP + ln4 -> d_out (fp32)
    mlp(inf(22), inf(23), inf(24), inf(25), inf(26), inf(27), d_out, 1);
}